// Round 13
// baseline (458.553 us; speedup 1.0000x reference)
//
#include <hip/hip_runtime.h>
#include <stdint.h>

typedef unsigned short u16;
typedef __attribute__((ext_vector_type(4))) short s16x4;
typedef __attribute__((ext_vector_type(8))) short short8;
typedef __attribute__((ext_vector_type(4))) float f32x4;
typedef __attribute__((ext_vector_type(16))) float f32x16;

// ---------- bf16 helpers (RNE) ----------
static __device__ __forceinline__ u16 f2bf(float f) {
    union { float f; uint32_t u; } c; c.f = f;
    uint32_t u = c.u;
    u += 0x7FFFu + ((u >> 16) & 1u);
    return (u16)(u >> 16);
}

// ---------- problem constants ----------
#define D_IN   2048
#define D_OUT  2048
#define MTOT   32768   // B*T
#define BK     64
#define NTM    32      // main K-tiles; tile 32 = LoRA tail

// Fragment-linear layouts (32x32x16 MFMA fragments, 1 KB each = 64 lanes x 16 B):
//   A-frag/B-frag (blk, ks): lane l holds rows blk*32+(l&31), cols ks*16+(l>>5)*8 .. +7
//   Wb:  [npanel 0..7][kt 0..31][frag = nb*4+ks][lane*8 + sub]   (16384 elems per (np,kt))
//   Bp:  [a][npanel][frag][lane*8+sub]                            (131072 elems per a)
//   xa:  [mpanel 0..127][frag = mb*4+ks][lane*8+sub]              (16384 elems per panel)

// async global->LDS, 16B/lane; LDS dest = wavebase + lane*16 (linear)
__device__ __forceinline__ void gload16(const u16* g, u16* l) {
    __builtin_amdgcn_global_load_lds(
        (const __attribute__((address_space(1))) void*)g,
        (__attribute__((address_space(3))) void*)l, 16, 0, 0);
}

// ---------- fused tiny preps: cast W (frag-order), build Apad, build Bpad (frag-order) ----------
__global__ __launch_bounds__(256) void k_prep(
    const float* __restrict__ W, const float* __restrict__ A, const float* __restrict__ Bm,
    u16* __restrict__ Wb, u16* __restrict__ Ap, u16* __restrict__ Bp)
{
    const int b = blockIdx.x, tid = threadIdx.x;
    if (b < 2048) {                       // W cast: 4M elems, 8/thread -> fragment order
        int i = (b * 256 + tid) * 8;
        int n = i >> 11, c = i & 2047;
        const float4* p = (const float4*)(W + i);
        float4 v0 = p[0], v1 = p[1];
        short8 o;
        o[0]=f2bf(v0.x); o[1]=f2bf(v0.y); o[2]=f2bf(v0.z); o[3]=f2bf(v0.w);
        o[4]=f2bf(v1.x); o[5]=f2bf(v1.y); o[6]=f2bf(v1.z); o[7]=f2bf(v1.w);
        const int np = n >> 8, kt = c >> 6, nb = (n & 255) >> 5, ks = (c >> 4) & 3;
        const int lane = (n & 31) + (((c >> 3) & 1) << 5);
        *(short8*)(Wb + (((size_t)(np << 5) + kt) << 14) + (((nb << 2) + ks) << 9) + (lane << 3)) = o;
    } else if (b < 6144) {                // Apad (a,64,d) row-major, rows 16..63 zero (for k_xa)
        int i = (b - 2048) * 256 + tid;
        int d = i & 2047, r = (i >> 11) & 63, a = i >> 17;
        Ap[i] = (r < 16) ? f2bf(A[(((a << 4) + r) << 11) + d]) : (u16)0;
    } else {                              // Bpad (a,n,64) -> fragment order, cols 16..63 zero
        int i = (b - 6144) * 256 + tid;
        int j = i & 63, n = (i >> 6) & 2047, a = i >> 17;
        float v = (j < 16) ? Bm[((((a << 11) + n)) << 4) + j] : 0.0f;
        const int np = n >> 8, nb = (n & 255) >> 5, ks = j >> 4;
        const int lane = (n & 31) + (((j >> 3) & 1) << 5), sub = j & 7;
        Bp[((size_t)a << 17) + ((size_t)np << 14) + (((nb << 2) + ks) << 9) + (lane << 3) + sub] = f2bf(v);
    }
}

// ---------- fused: x fp32 -> xb bf16 AND xa = s*(x @ Apad^T) (xa written frag-order) ----------
__global__ __launch_bounds__(256) void k_cast_x_xa(
    const float* __restrict__ x, const u16* __restrict__ Ap,
    const float* __restrict__ scal, const int* __restrict__ aidx,
    u16* __restrict__ xb, u16* __restrict__ xa)
{
    __shared__ __align__(16) u16 Xs[128 * BK];
    __shared__ __align__(16) u16 Ps[64 * BK];
    const int tid = threadIdx.x, lane = tid & 63, wid = tid >> 6;
    const int m0 = blockIdx.x << 7;
    const int a = aidx[m0 >> 11];
    const float s = scal[a];
    const int wr = wid >> 1, wc = wid & 1;
    const int arow = (wr << 6) + (lane & 15);
    const int brow = (wc << 5) + (lane & 15);
    const int scol = ((lane & 7) ^ (lane >> 3)) << 3;

    f32x4 acc[4][2];
    #pragma unroll
    for (int i = 0; i < 4; ++i) { acc[i][0] = 0.f; acc[i][1] = 0.f; }

    const int xrow_l = tid >> 4;
    const int xcol   = (tid & 15) << 2;
    const int wslot  = (tid & 15) >> 1;
    const int wsub   = (tid & 1) << 2;

    const u16* apg = Ap + ((size_t)a << 17);
    const u16* gP[2]; u16* lP[2];
    #pragma unroll
    for (int it = 0; it < 2; ++it) {
        const int chunk = (wid << 1) + it;
        const int row = (chunk << 3) + (lane >> 3);
        gP[it] = apg + ((size_t)row << 11) + scol;
        lP[it] = Ps + (chunk << 9) + (lane << 3);
    }

    for (int kt = 0; kt < NTM; ++kt) {
        const int k0 = kt << 6;
        float4 xv[8];
        #pragma unroll
        for (int r = 0; r < 8; ++r)
            xv[r] = *(const float4*)(x + ((size_t)(m0 + (r << 4) + xrow_l) << 11) + k0 + xcol);
        #pragma unroll
        for (int r = 0; r < 8; ++r) {
            const int row = (r << 4) + xrow_l;
            s16x4 c4;
            c4[0]=f2bf(xv[r].x); c4[1]=f2bf(xv[r].y); c4[2]=f2bf(xv[r].z); c4[3]=f2bf(xv[r].w);
            *(s16x4*)(Xs + (row << 6) + ((wslot ^ (row & 7)) << 3) + wsub) = c4;
            *(s16x4*)(xb + ((size_t)(m0 + row) << 11) + k0 + xcol) = c4;
        }
        gload16(gP[0] + k0, lP[0]);
        gload16(gP[1] + k0, lP[1]);
        asm volatile("s_waitcnt vmcnt(0)" ::: "memory");
        __syncthreads();
        #pragma unroll
        for (int kk = 0; kk < 2; ++kk) {
            const int sl = ((kk << 2) + (lane >> 4)) ^ (lane & 7);
            short8 af[4], bv[2];
            #pragma unroll
            for (int mi = 0; mi < 4; ++mi)
                af[mi] = *(const short8*)(Xs + ((arow + mi * 16) << 6) + (sl << 3));
            #pragma unroll
            for (int ni = 0; ni < 2; ++ni)
                bv[ni] = *(const short8*)(Ps + ((brow + ni * 16) << 6) + (sl << 3));
            #pragma unroll
            for (int mi = 0; mi < 4; ++mi)
                #pragma unroll
                for (int ni = 0; ni < 2; ++ni)
                    acc[mi][ni] = __builtin_amdgcn_mfma_f32_16x16x32_bf16(af[mi], bv[ni], acc[mi][ni], 0, 0, 0);
        }
        __syncthreads();
    }

    // epilogue -> xa in FRAGMENT order
    #pragma unroll
    for (int mi = 0; mi < 4; ++mi) {
        #pragma unroll
        for (int ni = 0; ni < 2; ++ni) {
            const int cc = (wc << 5) + ni * 16 + (lane & 15);
            #pragma unroll
            for (int rr = 0; rr < 4; ++rr) {
                const int mm = m0 + (wr << 6) + mi * 16 + ((lane >> 4) << 2) + rr;
                const int p = mm >> 8, r = mm & 255;
                const int mb = r >> 5, ks = cc >> 4;
                const int fl = (r & 31) + (((cc >> 3) & 1) << 5), sub = cc & 7;
                xa[((size_t)p << 14) + (((mb << 2) + ks) << 9) + (fl << 3) + sub] =
                    f2bf(acc[mi][ni][rr] * s);
            }
        }
    }
}

// ---------- main GEMM: 256x256, BK=64, 8 waves, FRAGMENT-LINEAR LDS + 32x32x16 MFMA,
// reg-pipelined 4-phase (preload ks+1, LGK(6)), stage@Phi0, vmcnt(0)+BAR@Phi3 ----------
__global__ __launch_bounds__(512, 2) void k_gemm(
    const u16* __restrict__ xb, const u16* __restrict__ Wb,
    const u16* __restrict__ xa, const u16* __restrict__ Bp,
    const int* __restrict__ aidx, float* __restrict__ out)
{
    __shared__ __align__(16) u16 LDS[2 * 32768];   // [buf][A 32KB | B 32KB]
    const int tid = threadIdx.x, lane = tid & 63, wid = tid >> 6;

    // XCD-aware bijective swizzle (1024 blocks, n-major within XCD chunk)
    const int newbid = (blockIdx.x & 7) * 128 + (blockIdx.x >> 3);
    const int bm = newbid >> 3, bn = newbid & 7;
    const int m0 = bm << 8, n0 = bn << 8;
    const int wr = wid >> 2, wc = wid & 3;          // 2M x 4N waves; wave tile 128x64
    const int a = aidx[m0 >> 11];

    f32x16 acc[4][2];                               // 4 m-blocks x 2 n-blocks of 32x32
    #pragma unroll
    for (int i = 0; i < 4; ++i)
        #pragma unroll
        for (int j = 0; j < 2; ++j)
            #pragma unroll
            for (int r = 0; r < 16; ++r) acc[i][j][r] = 0.0f;

    // ---- staging sources: wave wid stages A-frags (mb=wid, ks=j) + B-frags (nb=wid, ks=j)
    // main A from row-major xb: per-lane remapped source (32-B segments)
    const u16* sA = xb + ((size_t)(m0 + (wid << 5) + (lane & 31)) << 11) + ((lane >> 5) << 3);
    // main B from fragment-order Wb: fully linear
    const u16* sB = Wb + ((size_t)(bn << 5) << 14) + ((wid << 2) << 9) + (lane << 3);
    // tail A from fragment-order xa: linear
    const u16* sTA = xa + ((size_t)(m0 >> 8) << 14) + ((wid << 2) << 9) + (lane << 3);
    // tail B from fragment-order Bp: linear
    const u16* sTB = Bp + ((size_t)a << 17) + ((size_t)bn << 14) + ((wid << 2) << 9) + (lane << 3);
    u16* dA = &LDS[((wid << 2) << 9) + (lane << 3)];
    u16* dB = &LDS[16384 + ((wid << 2) << 9) + (lane << 3)];

    #define STAGE(tt, bb) do {                                                      \
        if ((tt) < NTM) {                                                           \
            const u16* a_ = sA + ((tt) << 6);                                       \
            _Pragma("unroll")                                                       \
            for (int j = 0; j < 4; ++j) gload16(a_ + (j << 4), dA + ((bb) << 15) + (j << 9)); \
            const u16* b_ = sB + ((size_t)(tt) << 14);                              \
            _Pragma("unroll")                                                       \
            for (int j = 0; j < 4; ++j) gload16(b_ + (j << 9), dB + ((bb) << 15) + (j << 9)); \
        } else {                                                                    \
            _Pragma("unroll")                                                       \
            for (int j = 0; j < 4; ++j) gload16(sTA + (j << 9), dA + ((bb) << 15) + (j << 9)); \
            _Pragma("unroll")                                                       \
            for (int j = 0; j < 4; ++j) gload16(sTB + (j << 9), dB + ((bb) << 15) + (j << 9)); \
        } } while (0)

    short8 afP[4], bvP[2], afQ[4], bvQ[2];

    // fragment-linear reads: base + compile-time frag offset + lane*16B  -> 0 conflicts
    #define RD(S, c_, ks_) do { _Pragma("unroll")                                   \
        for (int mi = 0; mi < 4; ++mi)                                              \
            af##S[mi] = *(const short8*)&LDS[((c_) << 15) +                         \
                (((wr << 4) + (mi << 2) + (ks_)) << 9) + (lane << 3)];              \
        _Pragma("unroll")                                                           \
        for (int i = 0; i < 2; ++i)                                                 \
            bv##S[i] = *(const short8*)&LDS[((c_) << 15) + 16384 +                  \
                (((wc << 3) + (i << 2) + (ks_)) << 9) + (lane << 3)];               \
        } while (0)

    #define BAR __builtin_amdgcn_s_barrier()
    #define VM0 asm volatile("s_waitcnt vmcnt(0)" ::: "memory")
    #define LGK(n) do { asm volatile("s_waitcnt lgkmcnt(" #n ")" ::: "memory");     \
                        __builtin_amdgcn_sched_barrier(0); } while (0)

    #define MM(S) do { __builtin_amdgcn_s_setprio(1); _Pragma("unroll")             \
        for (int mi = 0; mi < 4; ++mi) _Pragma("unroll")                            \
        for (int i = 0; i < 2; ++i)                                                 \
            acc[mi][i] = __builtin_amdgcn_mfma_f32_32x32x16_bf16(                   \
                af##S[mi], bv##S[i], acc[mi][i], 0, 0, 0);                          \
        __builtin_amdgcn_s_setprio(0); } while (0)

    // prologue: stage tile 0 -> buf 0; preload ks0 into P
    STAGE(0, 0);
    VM0;
    BAR;
    RD(P, 0, 0);

    for (int t = 0; t <= NTM; ++t) {
        const int c = t & 1, cn = c ^ 1;
        // Phi0: preload ks1 -> Q; stage tile t+1 -> cn; retire ks0 reads; MFMA ks0
        RD(Q, c, 1);
        if (t < NTM) STAGE(t + 1, cn);
        LGK(6); MM(P);
        // Phi1: preload ks2 -> P; retire ks1; MFMA ks1
        RD(P, c, 2);
        LGK(6); MM(Q);
        // Phi2: preload ks3 -> Q; retire ks2; MFMA ks2
        RD(Q, c, 3);
        LGK(6); MM(P);
        // Phi3: staging visible; preload next-tile ks0 -> P; retire ks3; MFMA ks3
        if (t < NTM) {
            VM0; BAR;
            RD(P, cn, 0);
            LGK(6); MM(Q);
            BAR;
        } else {
            LGK(0); MM(Q);
        }
    }

    #undef MM
    #undef LGK
    #undef VM0
    #undef BAR
    #undef RD
    #undef STAGE

    // epilogue: 32x32 C layout — col = lane&31, row = (reg&3) + 8*(reg>>2) + 4*(lane>>5)
    const int l31 = lane & 31, h5 = lane >> 5;
    #pragma unroll
    for (int mi = 0; mi < 4; ++mi) {
        #pragma unroll
        for (int i = 0; i < 2; ++i) {
            const int nn = n0 + (wc << 6) + (i << 5) + l31;
            #pragma unroll
            for (int r = 0; r < 16; ++r) {
                const int row = (r & 3) + ((r >> 2) << 3) + (h5 << 2);
                const int mm = m0 + (wr << 7) + (mi << 5) + row;
                out[((size_t)mm << 11) + nn] = acc[mi][i][r];
            }
        }
    }
}

extern "C" void kernel_launch(void* const* d_in, const int* in_sizes, int n_in,
                              void* d_out, int out_size, void* d_ws, size_t ws_size,
                              hipStream_t stream) {
    const float* x  = (const float*)d_in[0];
    const float* W  = (const float*)d_in[1];
    const float* A  = (const float*)d_in[2];
    const float* Bm = (const float*)d_in[3];
    const float* sc = (const float*)d_in[4];
    const int* aidx = (const int*)d_in[5];
    float* out = (float*)d_out;

    // ws layout (bytes): xb 128MiB | Wb 8MiB | Apad 2MiB | Bp 2MiB | xa 4MiB = 144 MiB
    char* ws = (char*)d_ws;
    u16* xb = (u16*)(ws);
    u16* Wb = (u16*)(ws + 134217728);
    u16* Ap = (u16*)(ws + 134217728 + 8388608);
    u16* Bp = (u16*)(ws + 134217728 + 8388608 + 2097152);
    u16* xa = (u16*)(ws + 134217728 + 8388608 + 2097152 + 2097152);

    hipLaunchKernelGGL(k_prep,      dim3(10240), dim3(256), 0, stream, W, A, Bm, Wb, Ap, Bp);
    hipLaunchKernelGGL(k_cast_x_xa, dim3(256),   dim3(256), 0, stream, x, Ap, sc, aidx, xb, xa);
    hipLaunchKernelGGL(k_gemm,      dim3(1024),  dim3(512), 0, stream, xb, Wb, xa, Bp, aidx, out);
}